// Round 1
// baseline (397.709 us; speedup 1.0000x reference)
//
#include <hip/hip_runtime.h>
#include <cstdint>
#include <cstddef>

#define BB   64
#define TT   512
#define CC   300
#define NG1  150    // conv1 groups (2 in-ch, 6 out-ch each)
#define OC1  900
#define L1   518    // conv1 output length (T + 6)
#define K1   256    // static max k for layer-1 kmax
#define NG2  75     // conv2 groups (2 in-ch = 12 y1 rows, 14 out-ch each)
#define W2LEN 260   // K1 + 4

__device__ __forceinline__ unsigned f2key(float f) {
    unsigned u = __float_as_uint(f);
    // monotone map: float order -> unsigned order
    return (u & 0x80000000u) ? ~u : (u | 0x80000000u);
}

__global__ void init_out(const float* __restrict__ bfc, float* __restrict__ out) {
    int i = threadIdx.x;            // 128 threads, out is [64,2]
    if (i < 2 * BB) out[i] = (i & 1) ? bfc[0] : 0.0f;
}

// One block per (group g, batch b). 384 threads = 6 waves; wave r owns out-channel g*6+r.
__global__ __launch_bounds__(384) void conv1_kmax(
    const float* __restrict__ x, const int* __restrict__ lengths,
    const float* __restrict__ w1, const float* __restrict__ b1,
    float* __restrict__ y1)
{
    const int g   = blockIdx.x;     // 0..149
    const int b   = blockIdx.y;     // 0..63
    const int tid = threadIdx.x;
    const int len = lengths[b];
    const int n   = len + 6;                    // valid conv1 prefix (<= 518)
    const int k   = max(4, (len + 1) >> 1);     // per-sample k (<= 256)

    __shared__ float xs[2][524];    // input t' in [-6, 517] -> idx t'+6
    __shared__ float hrow[6][584];  // conv out rows (padded so t up to 575 is in-bounds)
    __shared__ float ws1[84];       // 6 oc x 2 ic x 7 taps
    __shared__ float bs1[6];

    if (tid < 84) ws1[tid] = w1[g * 84 + tid];
    if (tid < 6)  bs1[tid] = b1[g * 6 + tid];

    for (int p = tid; p < 2 * 524; p += 384) {
        int ic = p / 524, q = p - ic * 524;
        int t  = q - 6;
        float v = 0.0f;
        if (t >= 0 && t < len) v = x[((size_t)b * TT + t) * CC + (2 * g + ic)];
        xs[ic][q] = v;
    }
    __syncthreads();

    // conv: h[r][t] = b1 + sum_{ic,kk} x[t-6+kk][2g+ic] * w1[g*6+r][ic][kk]
    for (int i = tid; i < 6 * L1; i += 384) {
        int r = i / L1, t = i - r * L1;
        if (t < n) {
            float acc = bs1[r];
            #pragma unroll
            for (int ic = 0; ic < 2; ++ic)
                #pragma unroll
                for (int kk = 0; kk < 7; ++kk)
                    acc = fmaf(xs[ic][t + kk], ws1[r * 14 + ic * 7 + kk], acc);
            hrow[r][t] = acc;
        }
    }
    __syncthreads();

    // per-wave order-preserving top-k over hrow[r][0..n)
    const int r    = tid >> 6;
    const int lane = tid & 63;

    float    v[9];
    unsigned key[9];
    #pragma unroll
    for (int j = 0; j < 9; ++j) {
        int  t     = lane + 64 * j;
        bool valid = (t < n);
        float vv   = hrow[r][t];        // rows padded; garbage beyond n unused
        v[j]   = valid ? vv : 0.0f;
        key[j] = valid ? f2key(vv) : 0u;    // finite floats map to keys >= 0x00800000
    }

    // binary search for tau = key of k-th largest
    unsigned lo = 1u, hi = 0xFFFFFFFFu;
    while (lo < hi) {
        unsigned mid = lo + ((hi - lo + 1) >> 1);
        int c = 0;
        #pragma unroll
        for (int j = 0; j < 9; ++j) c += (key[j] >= mid) ? 1 : 0;
        for (int o = 32; o; o >>= 1) c += __shfl_xor(c, o);
        if (c >= k) lo = mid; else hi = mid - 1;
    }
    const unsigned tau = lo;

    int cg = 0;
    #pragma unroll
    for (int j = 0; j < 9; ++j) cg += (key[j] > tau) ? 1 : 0;
    for (int o = 32; o; o >>= 1) cg += __shfl_xor(cg, o);
    const int budget = k - cg;      // ties (== tau) kept, earliest-index first

    float* outrow = y1 + ((size_t)(b * OC1 + g * 6 + r)) * K1;
    const unsigned long long below = (1ull << lane) - 1ull;

    int baseG = 0, baseE = 0;
    #pragma unroll
    for (int j = 0; j < 9; ++j) {
        bool isG = key[j] > tau;
        bool isE = (key[j] == tau);     // invalid slots have key 0 != tau
        unsigned long long mG = __ballot(isG);
        unsigned long long mE = __ballot(isE);
        int A = baseG + __popcll(mG & below);   // # greater before t
        int E = baseE + __popcll(mE & below);   // # equal before t
        if (isG || (isE && E < budget)) {
            int pos = A + (E < budget ? E : budget);
            outrow[pos] = tanhf(v[j]);
        }
        baseG += __popcll(mG);
        baseE += __popcll(mE);
    }
    for (int w = k + lane; w < K1; w += 64) outrow[w] = 0.0f;   // zero-pad tail
}

// One block per (group g2, batch b). conv2 (14 oc x (k1+4) pos) -> top-4 in order
// -> tanh -> dot with wfc slice -> atomicAdd into out[b][1].
__global__ __launch_bounds__(256) void conv2_kmax_fc(
    const float* __restrict__ y1, const int* __restrict__ lengths,
    const float* __restrict__ w2, const float* __restrict__ b2,
    const float* __restrict__ wfc, float* __restrict__ out)
{
    const int g   = blockIdx.x;     // 0..74
    const int b   = blockIdx.y;
    const int tid = threadIdx.x;
    const int len = lengths[b];
    const int k1  = max(4, (len + 1) >> 1);
    const int n2  = k1 + 4;         // valid conv2 prefix (<= 260)

    __shared__ float ys[12][264];   // y1 rows 12g..12g+12, w' in [-4, 260)
    __shared__ float hs[14][264];
    __shared__ float ws2[14 * 60];
    __shared__ float bs2[14];
    __shared__ float partial[14];

    for (int i = tid; i < 14 * 60; i += 256) ws2[i] = w2[(size_t)g * 840 + i];
    if (tid < 14) bs2[tid] = b2[g * 14 + tid];

    for (int i = tid; i < 12 * 264; i += 256) {
        int c = i / 264, p = i - c * 264;
        int w = p - 4;
        float vv = 0.0f;
        if (w >= 0 && w < K1) vv = y1[((size_t)(b * OC1 + g * 12 + c)) * K1 + w];
        ys[c][p] = vv;
    }
    __syncthreads();

    // conv2: hs[r2][w] = b2 + sum_{c=icl*6+kh, kw} ys[c][w+kw] * w2[g*14+r2][c*5+kw]
    for (int i = tid; i < 14 * W2LEN; i += 256) {
        int r2 = i / W2LEN, w = i - r2 * W2LEN;
        if (w < n2) {
            float acc = bs2[r2];
            #pragma unroll
            for (int c = 0; c < 12; ++c)
                #pragma unroll
                for (int kw = 0; kw < 5; ++kw)
                    acc = fmaf(ys[c][w + kw], ws2[r2 * 60 + c * 5 + kw], acc);
            hs[r2][w] = acc;
        }
    }
    __syncthreads();

    if (tid < 14) {
        const int r2 = tid;
        // order-preserving top-4: keep 4 best by (val desc, idx asc), then sort by idx
        float tv0 = -INFINITY, tv1 = -INFINITY, tv2 = -INFINITY, tv3 = -INFINITY;
        int   ti0 = 1 << 30,   ti1 = 1 << 30,   ti2 = 1 << 30,   ti3 = 1 << 30;
        for (int w = 0; w < n2; ++w) {
            float vv = hs[r2][w];
            if (vv > tv3) {
                if (vv > tv0)      { tv3=tv2; ti3=ti2; tv2=tv1; ti2=ti1; tv1=tv0; ti1=ti0; tv0=vv; ti0=w; }
                else if (vv > tv1) { tv3=tv2; ti3=ti2; tv2=tv1; ti2=ti1; tv1=vv; ti1=w; }
                else if (vv > tv2) { tv3=tv2; ti3=ti2; tv2=vv; ti2=w; }
                else               { tv3=vv; ti3=w; }
            }
        }
        // sort the 4 kept by index ascending (indices distinct)
        #define CSWAP(a,bq) if (ti##a > ti##bq) { int t_=ti##a; ti##a=ti##bq; ti##bq=t_; float f_=tv##a; tv##a=tv##bq; tv##bq=f_; }
        CSWAP(0,1) CSWAP(2,3) CSWAP(0,2) CSWAP(1,3) CSWAP(1,2)
        #undef CSWAP
        const int f = r2 * 75 + g;      // feature index after reshape/transpose
        float s = 0.0f;
        s += tanhf(tv0) * wfc[0 * 1050 + f];
        s += tanhf(tv1) * wfc[1 * 1050 + f];
        s += tanhf(tv2) * wfc[2 * 1050 + f];
        s += tanhf(tv3) * wfc[3 * 1050 + f];
        partial[r2] = s;
    }
    __syncthreads();

    if (tid == 0) {
        float s = 0.0f;
        #pragma unroll
        for (int i = 0; i < 14; ++i) s += partial[i];
        atomicAdd(&out[b * 2 + 1], s);
    }
}

extern "C" void kernel_launch(void* const* d_in, const int* in_sizes, int n_in,
                              void* d_out, int out_size, void* d_ws, size_t ws_size,
                              hipStream_t stream) {
    const float* x       = (const float*)d_in[0];
    const int*   lengths = (const int*)  d_in[1];
    const float* w1      = (const float*)d_in[2];
    const float* b1      = (const float*)d_in[3];
    const float* w2      = (const float*)d_in[4];
    const float* b2      = (const float*)d_in[5];
    const float* wfc     = (const float*)d_in[6];
    const float* bfc     = (const float*)d_in[7];
    float* out = (float*)d_out;
    float* y1  = (float*)d_ws;      // [64][900][256] f32 = 58.98 MB

    init_out<<<dim3(1), dim3(128), 0, stream>>>(bfc, out);
    conv1_kmax<<<dim3(NG1, BB), dim3(384), 0, stream>>>(x, lengths, w1, b1, y1);
    conv2_kmax_fc<<<dim3(NG2, BB), dim3(256), 0, stream>>>(y1, lengths, w2, b2, wfc, out);
}

// Round 3
// 396.228 us; speedup vs baseline: 1.0037x; 1.0037x over previous
//
#include <hip/hip_runtime.h>
#include <cstdint>
#include <cstddef>

#define BB   64
#define TT   512
#define CC   300
#define NG1  150    // conv1 groups (2 in-ch, 6 out-ch each)
#define OC1  900
#define L1   518    // conv1 output length (T + 6)
#define K1   256    // static max k for layer-1 kmax
#define NG2  75     // conv2 groups (2 in-ch = 12 y1 rows, 14 out-ch each)
#define W2LEN 260   // K1 + 4

__device__ __forceinline__ unsigned f2key(float f) {
    unsigned u = __float_as_uint(f);
    return (u & 0x80000000u) ? ~u : (u | 0x80000000u);   // monotone float->uint
}
__device__ __forceinline__ float key2f(unsigned k) {
    unsigned u = (k & 0x80000000u) ? (k & 0x7FFFFFFFu) : ~k;
    return __uint_as_float(u);
}
__device__ __forceinline__ unsigned long long packvi(float v, int w) {
    // value descending, then index ascending (top_k tie rule)
    return ((unsigned long long)f2key(v) << 32) | (unsigned)(~(unsigned)w);
}

__global__ void init_out(const float* __restrict__ bfc, float* __restrict__ out) {
    int i = threadIdx.x;
    if (i < 2 * BB) out[i] = (i & 1) ? bfc[0] : 0.0f;
}

// One block per (group g, batch b). 384 threads = 6 waves; wave r owns channel g*6+r.
// Conv straight into registers; ballot-count binary search for the k-th key.
__global__ __launch_bounds__(384) void conv1_kmax(
    const float* __restrict__ x, const int* __restrict__ lengths,
    const float* __restrict__ w1, const float* __restrict__ b1,
    float* __restrict__ y1)
{
    const int g   = blockIdx.x;
    const int b   = blockIdx.y;
    const int tid = threadIdx.x;
    const int len = lengths[b];
    const int n   = len + 6;                    // valid conv1 prefix (<= 518)
    const int k   = max(4, (len + 1) >> 1);     // per-sample k (<= 256)
    const int jmax = (n + 63) >> 6;             // <= 9, block-uniform

    __shared__ float xs[2][524];                // t' in [-6,518) -> idx t'+6
    __shared__ float ws1s[84];
    __shared__ float bs1s[6];

    if (tid < 84) ws1s[tid] = w1[g * 84 + tid];
    if (tid < 6)  bs1s[tid] = b1[g * 6 + tid];

    for (int p = tid; p < 2 * 524; p += 384) {
        int ic = (p >= 524) ? 1 : 0;
        int q  = p - ic * 524;
        int t  = q - 6;
        float v = 0.0f;
        if (t >= 0 && t < len) v = x[((size_t)b * TT + t) * CC + (2 * g + ic)];
        xs[ic][q] = v;
    }
    __syncthreads();

    const int r    = tid >> 6;
    const int lane = tid & 63;

    float wr[14];
    #pragma unroll
    for (int i = 0; i < 14; ++i) wr[i] = ws1s[r * 14 + i];   // uniform broadcast
    const float br = bs1s[r];

    float    v[9];
    unsigned key[9];
    #pragma unroll
    for (int j = 0; j < 9; ++j) {
        v[j] = 0.0f; key[j] = 0u;
        if (j < jmax) {                          // uniform branch
            int t = lane + 64 * j;
            if (t < n) {
                float acc = br;
                #pragma unroll
                for (int ic = 0; ic < 2; ++ic)
                    #pragma unroll
                    for (int kk = 0; kk < 7; ++kk)
                        acc = fmaf(xs[ic][t + kk], wr[ic * 7 + kk], acc);
                v[j]   = acc;
                key[j] = f2key(acc);             // finite float keys are > 0
            }
        }
    }

    // binary search for tau = key of k-th largest; count via ballot+popc (scalar pipe)
    unsigned lo = 1u, hi = 0xFFFFFFFFu;
    while (lo < hi) {
        unsigned mid = lo + ((hi - lo + 1) >> 1);
        int c = 0;
        #pragma unroll
        for (int j = 0; j < 9; ++j)
            if (j < jmax) c += (int)__popcll(__ballot(key[j] >= mid));
        if (c >= k) lo = mid; else hi = mid - 1;
    }
    const unsigned tau = lo;

    int cg = 0;
    #pragma unroll
    for (int j = 0; j < 9; ++j)
        if (j < jmax) cg += (int)__popcll(__ballot(key[j] > tau));
    const int budget = k - cg;                  // ties (== tau) kept earliest-first

    float* outrow = y1 + ((size_t)(b * OC1 + g * 6 + r)) * K1;
    const unsigned long long below = (1ull << lane) - 1ull;

    int baseG = 0, baseE = 0;
    #pragma unroll
    for (int j = 0; j < 9; ++j) {
        if (j < jmax) {
            bool isG = key[j] > tau;
            bool isE = (key[j] == tau);
            unsigned long long mG = __ballot(isG);
            unsigned long long mE = __ballot(isE);
            int A = baseG + (int)__popcll(mG & below);
            int E = baseE + (int)__popcll(mE & below);
            if (isG || (isE && E < budget)) {
                int pos = A + (E < budget ? E : budget);
                outrow[pos] = tanhf(v[j]);
            }
            baseG += (int)__popcll(mG);
            baseE += (int)__popcll(mE);
        }
    }
    for (int w = k + lane; w < K1; w += 64) outrow[w] = 0.0f;
}

// One block per (group g2, batch b). 4 waves; wave handles channels {wv, wv+4, ...}.
// Lane l computes 4 consecutive outputs from two ds_read_b128; top-4 via 4 rounds
// of wave-wide u64 argmax; tanh + wfc dot; one atomicAdd per wave.
__global__ __launch_bounds__(256) void conv2_kmax_fc(
    const float* __restrict__ y1, const int* __restrict__ lengths,
    const float* __restrict__ w2, const float* __restrict__ b2,
    const float* __restrict__ wfc, float* __restrict__ out)
{
    const int g   = blockIdx.x;
    const int b   = blockIdx.y;
    const int tid = threadIdx.x;
    const int len = lengths[b];
    const int k1  = max(4, (len + 1) >> 1);
    const int n2  = k1 + 4;                     // valid conv2 prefix (<= 260)

    __shared__ __align__(16) float ys[12][264]; // row stride 1056 B (16B multiple)
    __shared__ float ws2s[840];
    __shared__ float bs2s[14];

    for (int i = tid; i < 840; i += 256) ws2s[i] = w2[(size_t)g * 840 + i];
    if (tid < 14) bs2s[tid] = b2[g * 14 + tid];

    for (int i = tid; i < 12 * 264; i += 256) {
        int c = i / 264, p = i - c * 264;
        int w = p - 4;
        float vv = 0.0f;
        if (w >= 0 && w < K1) vv = y1[((size_t)(b * OC1 + g * 12 + c)) * K1 + w];
        ys[c][p] = vv;
    }
    __syncthreads();

    const int wv   = tid >> 6;
    const int lane = tid & 63;
    float wsum = 0.0f;

    for (int r2 = wv; r2 < 14; r2 += 4) {
        const float bias = bs2s[r2];
        float acc0 = bias, acc1 = bias, acc2 = bias, acc3 = bias;

        #pragma unroll 4
        for (int c = 0; c < 12; ++c) {
            const float4 f0 = *(const float4*)&ys[c][4 * lane];
            const float4 f1 = *(const float4*)&ys[c][4 * lane + 4];
            const float e0=f0.x,e1=f0.y,e2=f0.z,e3=f0.w,e4=f1.x,e5=f1.y,e6=f1.z,e7=f1.w;
            const float q0 = ws2s[r2*60 + c*5 + 0];
            const float q1 = ws2s[r2*60 + c*5 + 1];
            const float q2 = ws2s[r2*60 + c*5 + 2];
            const float q3 = ws2s[r2*60 + c*5 + 3];
            const float q4 = ws2s[r2*60 + c*5 + 4];
            acc0=fmaf(e0,q0,acc0); acc0=fmaf(e1,q1,acc0); acc0=fmaf(e2,q2,acc0); acc0=fmaf(e3,q3,acc0); acc0=fmaf(e4,q4,acc0);
            acc1=fmaf(e1,q0,acc1); acc1=fmaf(e2,q1,acc1); acc1=fmaf(e3,q2,acc1); acc1=fmaf(e4,q3,acc1); acc1=fmaf(e5,q4,acc1);
            acc2=fmaf(e2,q0,acc2); acc2=fmaf(e3,q1,acc2); acc2=fmaf(e4,q2,acc2); acc2=fmaf(e5,q3,acc2); acc2=fmaf(e6,q4,acc2);
            acc3=fmaf(e3,q0,acc3); acc3=fmaf(e4,q1,acc3); acc3=fmaf(e5,q2,acc3); acc3=fmaf(e6,q3,acc3); acc3=fmaf(e7,q4,acc3);
        }

        const int w0i = 4 * lane;
        unsigned long long cand0 = (w0i + 0 < n2) ? packvi(acc0, w0i + 0) : 0ull;
        unsigned long long cand1 = (w0i + 1 < n2) ? packvi(acc1, w0i + 1) : 0ull;
        unsigned long long cand2 = (w0i + 2 < n2) ? packvi(acc2, w0i + 2) : 0ull;
        unsigned long long cand3 = (w0i + 3 < n2) ? packvi(acc3, w0i + 3) : 0ull;
        unsigned long long cand4 = 0ull;
        if (n2 > 256) {                          // uniform; only longest samples
            if (lane < 4) {
                int w = 256 + lane;
                float a = bias;
                #pragma unroll
                for (int c = 0; c < 12; ++c)
                    #pragma unroll
                    for (int kw = 0; kw < 5; ++kw)
                        a = fmaf(ys[c][w + kw], ws2s[r2*60 + c*5 + kw], a);
                if (w < n2) cand4 = packvi(a, w);
            }
        }

        float tv[4]; int ti[4];
        #pragma unroll
        for (int round = 0; round < 4; ++round) {
            unsigned long long best = cand0;
            best = cand1 > best ? cand1 : best;
            best = cand2 > best ? cand2 : best;
            best = cand3 > best ? cand3 : best;
            best = cand4 > best ? cand4 : best;
            #pragma unroll
            for (int o = 32; o; o >>= 1) {
                unsigned bh = (unsigned)(best >> 32), bl = (unsigned)best;
                unsigned oh = __shfl_xor(bh, o),      ol = __shfl_xor(bl, o);
                unsigned long long other = ((unsigned long long)oh << 32) | ol;
                if (other > best) best = other;
            }
            ti[round] = (int)(~(unsigned)best);
            tv[round] = key2f((unsigned)(best >> 32));
            if (cand0 == best) cand0 = 0ull;    // keys unique (index-tagged)
            if (cand1 == best) cand1 = 0ull;
            if (cand2 == best) cand2 = 0ull;
            if (cand3 == best) cand3 = 0ull;
            if (cand4 == best) cand4 = 0ull;
        }
        // restore temporal order: sort 4 by index ascending
        #define CSW(a,bq) if (ti[a] > ti[bq]) { int t_=ti[a]; ti[a]=ti[bq]; ti[bq]=t_; float f_=tv[a]; tv[a]=tv[bq]; tv[bq]=f_; }
        CSW(0,1) CSW(2,3) CSW(0,2) CSW(1,3) CSW(1,2)
        #undef CSW

        const int f = r2 * 75 + g;
        float s = tanhf(tv[0]) * wfc[0 * 1050 + f];
        s = fmaf(tanhf(tv[1]), wfc[1 * 1050 + f], s);
        s = fmaf(tanhf(tv[2]), wfc[2 * 1050 + f], s);
        s = fmaf(tanhf(tv[3]), wfc[3 * 1050 + f], s);
        wsum += s;
    }

    if (lane == 0) atomicAdd(&out[b * 2 + 1], wsum);
}

extern "C" void kernel_launch(void* const* d_in, const int* in_sizes, int n_in,
                              void* d_out, int out_size, void* d_ws, size_t ws_size,
                              hipStream_t stream) {
    const float* x       = (const float*)d_in[0];
    const int*   lengths = (const int*)  d_in[1];
    const float* w1      = (const float*)d_in[2];
    const float* b1      = (const float*)d_in[3];
    const float* w2      = (const float*)d_in[4];
    const float* b2      = (const float*)d_in[5];
    const float* wfc     = (const float*)d_in[6];
    const float* bfc     = (const float*)d_in[7];
    float* out = (float*)d_out;
    float* y1  = (float*)d_ws;      // [64][900][256] f32 = 58.98 MB

    init_out<<<dim3(1), dim3(128), 0, stream>>>(bfc, out);
    conv1_kmax<<<dim3(NG1, BB), dim3(384), 0, stream>>>(x, lengths, w1, b1, y1);
    conv2_kmax_fc<<<dim3(NG2, BB), dim3(256), 0, stream>>>(y1, lengths, w2, b2, wfc, out);
}

// Round 4
// 335.140 us; speedup vs baseline: 1.1867x; 1.1823x over previous
//
#include <hip/hip_runtime.h>
#include <cstdint>
#include <cstddef>

#define BB   64
#define TT   512
#define CC   300
#define NG1  150    // conv1 groups (2 in-ch, 6 out-ch each)
#define OC1  900
#define K1   256    // static max k for layer-1 kmax
#define RS   264    // padded y1 row stride: [4 zero | 256 data | 4 zero]
#define NG2  75     // conv2 groups (12 y1 rows, 14 out-ch each)

__device__ __forceinline__ unsigned f2key(float f) {
    unsigned u = __float_as_uint(f);
    return (u & 0x80000000u) ? ~u : (u | 0x80000000u);   // monotone float->uint
}
__device__ __forceinline__ float key2f(unsigned k) {
    unsigned u = (k & 0x80000000u) ? (k & 0x7FFFFFFFu) : ~k;
    return __uint_as_float(u);
}
__device__ __forceinline__ float fast_tanh(float x) {
    // tanh = 1 - 2/(e^{2x}+1); v_exp + v_rcp, err ~1e-7, inf-safe for |x|<44
    float e = __expf(2.0f * x);
    return 1.0f - 2.0f * __builtin_amdgcn_rcpf(e + 1.0f);
}
__device__ __forceinline__ int mbcnt64(unsigned long long m) {
    // popc(m & ((1<<lane)-1)) across 64 lanes
    return (int)__builtin_amdgcn_mbcnt_hi((unsigned)(m >> 32),
                 __builtin_amdgcn_mbcnt_lo((unsigned)m, 0u));
}

__global__ void init_out(const float* __restrict__ bfc, float* __restrict__ out) {
    int i = threadIdx.x;
    if (i < 2 * BB) out[i] = (i & 1) ? bfc[0] : 0.0f;
}

// ---------------- conv1 + dynamic k-max (layer 1) ----------------
// Wave r owns channel g*6+r. Lane owns S consecutive positions t = S*lane + j.
// Selection: float-space bisection, exit on count==k (exact); tie fallback.
template<int S>
__device__ __forceinline__ void conv1_core(
    const float (* __restrict__ xs)[524], int lane, int n, int k,
    const float* wA, const float* wB, float br, float* __restrict__ row)
{
    constexpr int NV = (S == 8) ? 16 : 12;   // window floats loaded per lane
    const int t0 = S * lane;

    float xa[NV], xb[NV];
    #pragma unroll
    for (int q = 0; q < NV / 4; ++q) {
        *(float4*)&xa[4 * q] = *(const float4*)&xs[0][t0 + 4 * q];
        *(float4*)&xb[4 * q] = *(const float4*)&xs[1][t0 + 4 * q];
    }

    float v[S + 1];
    #pragma unroll
    for (int j = 0; j < S; ++j) {
        float acc = br;
        #pragma unroll
        for (int kk = 0; kk < 7; ++kk)
            acc = fmaf(xa[j + kk], wA[kk], fmaf(xb[j + kk], wB[kk], acc));
        v[j] = (t0 + j < n) ? acc : -INFINITY;
    }
    v[S] = -INFINITY;
    if (S == 8 && n > 512) {                 // tail t = 512..517, lanes 0..5
        if (lane < 6 && 512 + lane < n) {
            float acc = br;
            #pragma unroll
            for (int kk = 0; kk < 7; ++kk)
                acc = fmaf(xs[0][512 + lane + kk], wA[kk],
                      fmaf(xs[1][512 + lane + kk], wB[kk], acc));
            v[S] = acc;
        }
    }

    // wave min/max over valid values
    float lmax = -INFINITY, lmin = INFINITY;
    #pragma unroll
    for (int j = 0; j <= S; ++j) {
        lmax = fmaxf(lmax, v[j]);
        lmin = fminf(lmin, (v[j] == -INFINITY) ? INFINITY : v[j]);
    }
    #pragma unroll
    for (int o = 32; o; o >>= 1) {
        lmax = fmaxf(lmax, __shfl_xor(lmax, o));
        lmin = fminf(lmin, __shfl_xor(lmin, o));
    }
    const float vmax = lmax, vmin = lmin;

    // threshold search
    float tau; bool found = false;
    int cmax = 0;
    #pragma unroll
    for (int j = 0; j <= S; ++j) cmax += (int)__popcll(__ballot(v[j] == vmax));
    if (cmax >= k) {
        tau = vmax;                          // top-k all equal vmax: tie path
    } else {
        float lo = vmin, hi = vmax;          // inv: cnt(>=lo)>k, cnt(>=hi)<k
        tau = lo;
        while (true) {
            float mid = 0.5f * (lo + hi);
            if (mid == lo || mid == hi) { tau = lo; break; }   // (lo,hi) empty
            int c = 0;
            #pragma unroll
            for (int j = 0; j <= S; ++j)
                c += (int)__popcll(__ballot(v[j] >= mid));
            if (c == k) { tau = mid; found = true; break; }
            if (c > k) lo = mid; else hi = mid;
        }
    }

    // classify + stable emission (order = t ascending; lane-major layout)
    bool bG[S + 1], bE[S + 1];
    unsigned long long mG[S + 1], mE[S + 1];
    #pragma unroll
    for (int j = 0; j <= S; ++j) {
        bG[j] = found ? (v[j] >= tau) : (v[j] > tau);
        bE[j] = found ? false : (v[j] == tau);
        mG[j] = __ballot(bG[j]);
        mE[j] = __ballot(bE[j]);
    }
    int cg = 0;
    #pragma unroll
    for (int j = 0; j <= S; ++j) cg += (int)__popcll(mG[j]);
    const int budget = k - cg;               // found path: 0

    int SGm = 0, SEm = 0, FGm = 0, FEm = 0;
    #pragma unroll
    for (int j = 0; j < S; ++j) {
        SGm += mbcnt64(mG[j]);  FGm += (int)__popcll(mG[j]);
        SEm += mbcnt64(mE[j]);  FEm += (int)__popcll(mE[j]);
    }
    int ownG = 0, ownE = 0;
    #pragma unroll
    for (int j = 0; j < S; ++j) {            // main slots: t = S*lane + j
        if (bG[j] || bE[j]) {
            int E = SEm + ownE;
            if (bG[j] || E < budget) {
                int pos = SGm + ownG + min(E, budget);
                row[4 + pos] = fast_tanh(v[j]);
            }
        }
        ownG += bG[j] ? 1 : 0;  ownE += bE[j] ? 1 : 0;
    }
    if (S == 8 && (bG[S] || bE[S])) {        // tail: t >= 512 > all main t
        int E = FEm + mbcnt64(mE[S]);
        if (bG[S] || E < budget) {
            int pos = FGm + mbcnt64(mG[S]) + min(E, budget);
            row[4 + pos] = fast_tanh(v[S]);
        }
    }
    // zero pads: head [0,4), tail [4+k, 264)
    if (lane < 4) row[lane] = 0.0f;
    for (int w = k + lane; w < RS - 4; w += 64) row[4 + w] = 0.0f;
}

__global__ __launch_bounds__(384) void conv1_kmax(
    const float* __restrict__ x, const int* __restrict__ lengths,
    const float* __restrict__ w1, const float* __restrict__ b1,
    float* __restrict__ y1)
{
    const int g = blockIdx.x, b = blockIdx.y;
    const int tid = threadIdx.x;
    const int len = lengths[b];
    const int n = len + 6;
    const int k = max(4, (len + 1) >> 1);

    __shared__ __align__(16) float xs[2][524];
    __shared__ float ws[84];
    __shared__ float bs[6];
    if (tid < 84) ws[tid] = w1[g * 84 + tid];
    if (tid < 6)  bs[tid] = b1[g * 6 + tid];
    for (int p = tid; p < 1048; p += 384) {
        int ic = (p >= 524) ? 1 : 0;
        int q = p - ic * 524;
        int t = q - 6;
        xs[ic][q] = (t >= 0 && t < len) ? x[((size_t)b * TT + t) * CC + 2 * g + ic] : 0.0f;
    }
    __syncthreads();

    const int r = tid >> 6, lane = tid & 63;
    float wA[7], wB[7];
    #pragma unroll
    for (int i = 0; i < 7; ++i) { wA[i] = ws[r * 14 + i]; wB[i] = ws[r * 14 + 7 + i]; }
    const float br = bs[r];
    float* row = y1 + ((size_t)b * OC1 + g * 6 + r) * RS;

    if (n <= 256) conv1_core<4>(xs, lane, n, k, wA, wB, br, row);
    else          conv1_core<8>(xs, lane, n, k, wA, wB, br, row);
}

// ---------------- conv2 + k-max(4) + tanh + fc (fused) ----------------
// No LDS at all: y1 windows via global float4 (L1-hot), weights via scalar loads.
__global__ __launch_bounds__(256) void conv2_kmax_fc(
    const float* __restrict__ y1, const int* __restrict__ lengths,
    const float* __restrict__ w2, const float* __restrict__ b2,
    const float* __restrict__ wfc, float* __restrict__ out)
{
    const int g = blockIdx.x, b = blockIdx.y;
    const int tid = threadIdx.x;
    const int wv = tid >> 6, lane = tid & 63;
    const int len = lengths[b];
    const int k1 = max(4, (len + 1) >> 1);
    const int n2 = k1 + 4;                   // valid conv2 prefix (<= 260)

    const int r2u0 = __builtin_amdgcn_readfirstlane(4 * wv);  // wave-uniform sgpr
    const int nch  = (wv == 3) ? 2 : 4;      // channels r2 = r2u0 + it
    const float* __restrict__ wg = w2 + (size_t)g * 840;
    const float* base = y1 + ((size_t)b * OC1 + g * 12) * RS;

    float bias_s[4];
    #pragma unroll
    for (int it = 0; it < 4; ++it)
        bias_s[it] = (4 * wv + it < 14) ? b2[(size_t)g * 14 + r2u0 + it] : 0.0f;

    float acc[4][4];
    #pragma unroll
    for (int it = 0; it < 4; ++it)
        #pragma unroll
        for (int j = 0; j < 4; ++j) acc[it][j] = bias_s[it];

    // main conv: lane covers w = 4*lane .. 4*lane+3
    for (int c = 0; c < 12; ++c) {
        const float* rp = base + (size_t)c * RS;
        const float4 f0 = *(const float4*)&rp[4 * lane];
        const float4 f1 = *(const float4*)&rp[4 * lane + 4];
        const float e[8] = {f0.x, f0.y, f0.z, f0.w, f1.x, f1.y, f1.z, f1.w};
        #pragma unroll
        for (int it = 0; it < 4; ++it) {
            if (it < nch) {
                const float* wp = wg + (r2u0 + it) * 60 + c * 5;
                #pragma unroll
                for (int kw = 0; kw < 5; ++kw) {
                    const float q = wp[kw];
                    acc[it][0] = fmaf(e[0 + kw], q, acc[it][0]);
                    acc[it][1] = fmaf(e[1 + kw], q, acc[it][1]);
                    acc[it][2] = fmaf(e[2 + kw], q, acc[it][2]);
                    acc[it][3] = fmaf(e[3 + kw], q, acc[it][3]);
                }
            }
        }
    }

    // tail positions w = 256..259 (only when n2 > 256; rare)
    float tval[4];
    #pragma unroll
    for (int it = 0; it < 4; ++it) tval[it] = -INFINITY;
    if (n2 > 256) {
        if (lane < 4 && 256 + lane < n2) {
            const int w = 256 + lane;
            float ta[4];
            #pragma unroll
            for (int it = 0; it < 4; ++it) ta[it] = bias_s[it];
            for (int c = 0; c < 12; ++c) {
                const float* rp = base + (size_t)c * RS;
                #pragma unroll
                for (int kw = 0; kw < 5; ++kw) {
                    const float xv = rp[w + kw];
                    #pragma unroll
                    for (int it = 0; it < 4; ++it)
                        if (it < nch)
                            ta[it] = fmaf(xv, wg[(r2u0 + it) * 60 + c * 5 + kw], ta[it]);
                }
            }
            #pragma unroll
            for (int it = 0; it < 4; ++it) tval[it] = ta[it];
        }
    }

    // per-channel: order-preserving top-4 -> tanh -> fc dot
    float fcsum = 0.0f;
    #pragma unroll
    for (int it = 0; it < 4; ++it) {
        if (it < nch) {
            unsigned kk[5];
            #pragma unroll
            for (int j = 0; j < 4; ++j)
                kk[j] = (4 * lane + j < n2) ? f2key(acc[it][j]) : 0u;
            kk[4] = (tval[it] != -INFINITY) ? f2key(tval[it]) : 0u;

            float tv[4]; int ti[4];
            #pragma unroll
            for (int round = 0; round < 4; ++round) {
                unsigned best = max(max(kk[0], kk[1]), max(kk[2], kk[3]));
                best = max(best, kk[4]);
                #pragma unroll
                for (int o = 32; o; o >>= 1)
                    best = max(best, (unsigned)__shfl_xor((int)best, o));
                int jm = 5;
                #pragma unroll
                for (int j = 4; j >= 0; --j) if (kk[j] == best) jm = j;
                unsigned long long m = __ballot(jm < 5);
                int wl;
                if (__popcll(m) == 1) {
                    wl = __ffsll((long long)m) - 1;
                } else {                      // exact value tie: pick smallest t
                    int myt = (jm == 4) ? (256 + lane)
                            : (jm < 4 ? 4 * lane + jm : 0x7FFFFFFF);
                    int tmin = myt;
                    #pragma unroll
                    for (int o = 32; o; o >>= 1) tmin = min(tmin, __shfl_xor(tmin, o));
                    wl = __ffsll((long long)__ballot(myt == tmin)) - 1;
                }
                const int jw = __shfl(jm, wl);
                ti[round] = (jw == 4) ? (256 + wl) : (4 * wl + jw);
                tv[round] = key2f(best);
                #pragma unroll
                for (int j = 0; j < 5; ++j)   // consume (static indexing)
                    if (lane == wl && jm == j) kk[j] = 0u;
            }
            #define CSW(a,bq) if (ti[a] > ti[bq]) { int t_=ti[a]; ti[a]=ti[bq]; ti[bq]=t_; float f_=tv[a]; tv[a]=tv[bq]; tv[bq]=f_; }
            CSW(0,1) CSW(2,3) CSW(0,2) CSW(1,3) CSW(1,2)
            #undef CSW

            const float* wfp = wfc + (r2u0 + it) * 75 + g;   // scalar loads
            float s = fast_tanh(tv[0]) * wfp[0];
            s = fmaf(fast_tanh(tv[1]), wfp[1050], s);
            s = fmaf(fast_tanh(tv[2]), wfp[2100], s);
            s = fmaf(fast_tanh(tv[3]), wfp[3150], s);
            fcsum += s;
        }
    }
    if (lane == 0) atomicAdd(&out[b * 2 + 1], fcsum);
}

extern "C" void kernel_launch(void* const* d_in, const int* in_sizes, int n_in,
                              void* d_out, int out_size, void* d_ws, size_t ws_size,
                              hipStream_t stream) {
    const float* x       = (const float*)d_in[0];
    const int*   lengths = (const int*)  d_in[1];
    const float* w1      = (const float*)d_in[2];
    const float* b1      = (const float*)d_in[3];
    const float* w2      = (const float*)d_in[4];
    const float* b2      = (const float*)d_in[5];
    const float* wfc     = (const float*)d_in[6];
    const float* bfc     = (const float*)d_in[7];
    float* out = (float*)d_out;
    float* y1  = (float*)d_ws;      // [64][900][264] f32 = 60.8 MB padded rows

    init_out<<<dim3(1), dim3(128), 0, stream>>>(bfc, out);
    conv1_kmax<<<dim3(NG1, BB), dim3(384), 0, stream>>>(x, lengths, w1, b1, y1);
    conv2_kmax_fc<<<dim3(NG2, BB), dim3(256), 0, stream>>>(y1, lengths, w2, b2, wfc, out);
}